// Round 3
// baseline (275.222 us; speedup 1.0000x reference)
//
#include <hip/hip_runtime.h>

// ---------------------------------------------------------------- types
typedef __attribute__((ext_vector_type(8))) short bf16x8;   // 8 bf16 (4 VGPR)
typedef __attribute__((ext_vector_type(4))) float f32x4;
typedef __attribute__((ext_vector_type(2))) unsigned int u32x2;
typedef __attribute__((ext_vector_type(4))) unsigned int u32x4;

#define MFMA16(a, b, c) __builtin_amdgcn_mfma_f32_16x16x32_bf16((a), (b), (c), 0, 0, 0)

// B=4, S=2048, E=1024, H=16, D=64
#define S_LEN 2048
#define NHEAD 16
#define DHEAD 64
#define BH    64            // B*H
#define MROWS 8192          // B*S

__device__ __forceinline__ unsigned short f2bf(float f) {
  unsigned int u = __builtin_bit_cast(unsigned int, f);
  u += 0x7FFFu + ((u >> 16) & 1u);          // round-to-nearest-even
  return (unsigned short)(u >> 16);
}

__device__ __forceinline__ void gl_lds16(const void* g, void* l) {
  __builtin_amdgcn_global_load_lds(
      (const __attribute__((address_space(1))) void*)g,
      (__attribute__((address_space(3))) void*)l, 16, 0, 0);
}

// pack two fp32 -> (bf16(hi)<<16)|bf16(lo), round-half-up via add+perm
__device__ __forceinline__ unsigned int pkbf(float lo, float hi) {
  unsigned int ulo = __builtin_bit_cast(unsigned int, lo) + 0x8000u;
  unsigned int uhi = __builtin_bit_cast(unsigned int, hi) + 0x8000u;
  return __builtin_amdgcn_perm(uhi, ulo, 0x07060302u);
}

// ---------------------------------------------------------------- cast fp32 -> bf16
__global__ __launch_bounds__(256) void cast_bf16(const float* __restrict__ src,
                                                 unsigned short* __restrict__ dst, int n) {
  int i = (blockIdx.x * 256 + threadIdx.x) * 4;
  if (i + 3 < n) {
    f32x4 v = *(const f32x4*)(src + i);
    unsigned long long pk =
        (unsigned long long)f2bf(v[0]) |
        ((unsigned long long)f2bf(v[1]) << 16) |
        ((unsigned long long)f2bf(v[2]) << 32) |
        ((unsigned long long)f2bf(v[3]) << 48);
    *(unsigned long long*)(dst + i) = pk;
  }
}

// ---------------------------------------------------------------- transpose + cast (plain, for Wo)
__global__ __launch_bounds__(256) void transpose_cast(const float* __restrict__ src,
                                                      unsigned short* __restrict__ dst,
                                                      int R, int C) {
  __shared__ float tile[32][33];
  int c0 = blockIdx.x * 32, r0 = blockIdx.y * 32;
  int tx = threadIdx.x, ty = threadIdx.y;   // block (32,8)
  for (int i = 0; i < 32; i += 8)
    tile[ty + i][tx] = src[(size_t)(r0 + ty + i) * C + c0 + tx];
  __syncthreads();
  for (int i = 0; i < 32; i += 8)
    dst[(size_t)(c0 + ty + i) * R + r0 + tx] = f2bf(tile[tx][ty + i]);
}

// ---------------------------------------------------------------- transpose + cast + col-permute for Wqkv
// src [1024 k][3072 oc], oc = h*192 + which*64 + d  ->  dst[nc][1024], nc = which*1024 + h*64 + d
__global__ __launch_bounds__(256) void transpose_cast_qkv(const float* __restrict__ src,
                                                          unsigned short* __restrict__ dst) {
  __shared__ float tile[32][33];
  int c0 = blockIdx.x * 32, r0 = blockIdx.y * 32;
  int tx = threadIdx.x, ty = threadIdx.y;   // block (32,8)
  for (int i = 0; i < 32; i += 8)
    tile[ty + i][tx] = src[(size_t)(r0 + ty + i) * 3072 + c0 + tx];
  __syncthreads();
  for (int i = 0; i < 32; i += 8) {
    int oc = c0 + ty + i;
    int h = oc / 192, rr = oc % 192;
    int nc = ((rr >> 6) << 10) + (h << 6) + (rr & 63);
    dst[(size_t)nc * 1024 + r0 + tx] = f2bf(tile[tx][ty + i]);
  }
}

// ---------------------------------------------------------------- GEMM core (m97 structure, kept for gemm_out)
#define GEMM_CORE(A_, Bt_)                                                              \
  __shared__ unsigned short As[128 * 32];                                               \
  __shared__ unsigned short Bs[128 * 32];                                               \
  const int tid = threadIdx.x;                                                          \
  const int w = tid >> 6, lane = tid & 63, l15 = lane & 15, quad = lane >> 4;           \
  const int wm = w >> 1, wn = w & 1;                                                    \
  const int col0 = blockIdx.x * 128, row0 = blockIdx.y * 128;                           \
  f32x4 acc[4][4] = {};                                                                 \
  for (int kt = 0; kt < 32; ++kt) {                                                     \
    const int k0 = kt * 32;                                                             \
    for (int p = 0; p < 2; ++p) {                                                       \
      int c = p * 256 + tid;                                                            \
      int m = c >> 2, k8 = (c & 3) * 8;                                                 \
      void* ldsA = (char*)As + (size_t)(p * 256 + (tid & 192)) * 16;                    \
      void* ldsB = (char*)Bs + (size_t)(p * 256 + (tid & 192)) * 16;                    \
      gl_lds16(A_ + (size_t)(row0 + m) * 1024 + k0 + k8, ldsA);                         \
      gl_lds16(Bt_ + (size_t)(col0 + m) * 1024 + k0 + k8, ldsB);                        \
    }                                                                                   \
    __syncthreads();                                                                    \
    bf16x8 af[4], bfr[4];                                                               \
    for (int i = 0; i < 4; ++i)                                                         \
      af[i] = *(const bf16x8*)&As[(wm * 64 + i * 16 + l15) * 32 + quad * 8];            \
    for (int j = 0; j < 4; ++j)                                                         \
      bfr[j] = *(const bf16x8*)&Bs[(wn * 64 + j * 16 + l15) * 32 + quad * 8];           \
    for (int i = 0; i < 4; ++i)                                                         \
      for (int j = 0; j < 4; ++j)                                                       \
        acc[i][j] = MFMA16(af[i], bfr[j], acc[i][j]);                                   \
    __syncthreads();                                                                    \
  }

// ================================================================ gemm_qkv (128x256, balanced 3-round grid)
// Grid 64x12 = 768 blocks = EXACTLY 3 dispatch rounds at 1 block/CU (the 256x256/384-
// block versions ran 1.5 rounds -> 33% idle tail; all prior variants' 26-27% MfmaUtil
// decomposes as 44% window-serialization x 0.75 balance x epilogue).
// 8 waves (2Mx4N), wave tile 64x64, acc[4][4]. LDS 96KB: per buf A 2x8KB + B 2x16KB.
// Uniform single-barrier window per K-half (32 windows):
//   { stage 3 gl_lds; 16 MFMA (setP); 8 ds_read b128 (setR <- operands for W+1);
//     vmcnt(3); s_barrier }
// Safety: reads at W consume the batch staged at W-2, drained by W-1's VM3+barrier.
// sched_group_barrier pattern [3 VMEM][2 MFMA,1 DS_READ]x8 forces DS||MFMA pipe
// overlap inside the window (the measured 1400cy/window vs 700cy floor was the two
// pipes serializing under barrier-lockstep round-robin issue).

#define VM3 asm volatile("s_waitcnt vmcnt(3)" ::: "memory")
#define VM0 asm volatile("s_waitcnt vmcnt(0)" ::: "memory")
#define BAR __builtin_amdgcn_s_barrier()
#define SB  __builtin_amdgcn_sched_barrier(0)
#define SGB_G(m, n) __builtin_amdgcn_sched_group_barrier((m), (n), 0)

#define SGBPAT                                                                   \
  SGB_G(0x70, 3);                                                                \
  SGB_G(0x8, 2); SGB_G(0x100, 1); SGB_G(0x8, 2); SGB_G(0x100, 1);                \
  SGB_G(0x8, 2); SGB_G(0x100, 1); SGB_G(0x8, 2); SGB_G(0x100, 1);                \
  SGB_G(0x8, 2); SGB_G(0x100, 1); SGB_G(0x8, 2); SGB_G(0x100, 1);                \
  SGB_G(0x8, 2); SGB_G(0x100, 1); SGB_G(0x8, 2); SGB_G(0x100, 1)

// LDS map (bytes, per buffer stride 49152): A: kh*8192 + row*64 + q*16 (row<128)
//                                           B: 16384 + kh*16384 + row*64 + q*16 (row<256)
#define STAGE3(T, KH, BUF)                                                       \
  do {                                                                           \
    const unsigned short* ga_ = a_src + (T) * 64 + (KH) * 32;                    \
    const unsigned short* gb_ = b_src + (T) * 64 + (KH) * 32;                    \
    char* la_ = SHB + (BUF) * 49152 + (KH) * 8192 + stgo;                        \
    char* lb_ = SHB + (BUF) * 49152 + 16384 + (KH) * 16384 + stgo;               \
    gl_lds16(ga_, la_);                                                          \
    gl_lds16(gb_, lb_);                                                          \
    gl_lds16(gb_ + 131072, lb_ + 8192);                                          \
  } while (0)

#define RDSET(S, BUF, KH)                                                        \
  do {                                                                           \
    const char* Ab_ = SHB + (BUF) * 49152 + (KH) * 8192 + abase;                 \
    const char* Bb_ = SHB + (BUF) * 49152 + 16384 + (KH) * 16384 + bbase;        \
    af##S##0 = *(const bf16x8*)(Ab_);                                            \
    af##S##1 = *(const bf16x8*)(Ab_ + 1024);                                     \
    af##S##2 = *(const bf16x8*)(Ab_ + 2048);                                     \
    af##S##3 = *(const bf16x8*)(Ab_ + 3072);                                     \
    bq##S##0 = *(const bf16x8*)(Bb_);                                            \
    bq##S##1 = *(const bf16x8*)(Bb_ + 1024);                                     \
    bq##S##2 = *(const bf16x8*)(Bb_ + 2048);                                     \
    bq##S##3 = *(const bf16x8*)(Bb_ + 3072);                                     \
  } while (0)

#define MFMA16S(S)                                                               \
  acc[0][0] = MFMA16(af##S##0, bq##S##0, acc[0][0]);                             \
  acc[0][1] = MFMA16(af##S##0, bq##S##1, acc[0][1]);                             \
  acc[0][2] = MFMA16(af##S##0, bq##S##2, acc[0][2]);                             \
  acc[0][3] = MFMA16(af##S##0, bq##S##3, acc[0][3]);                             \
  acc[1][0] = MFMA16(af##S##1, bq##S##0, acc[1][0]);                             \
  acc[1][1] = MFMA16(af##S##1, bq##S##1, acc[1][1]);                             \
  acc[1][2] = MFMA16(af##S##1, bq##S##2, acc[1][2]);                             \
  acc[1][3] = MFMA16(af##S##1, bq##S##3, acc[1][3]);                             \
  acc[2][0] = MFMA16(af##S##2, bq##S##0, acc[2][0]);                             \
  acc[2][1] = MFMA16(af##S##2, bq##S##1, acc[2][1]);                             \
  acc[2][2] = MFMA16(af##S##2, bq##S##2, acc[2][2]);                             \
  acc[2][3] = MFMA16(af##S##2, bq##S##3, acc[2][3]);                             \
  acc[3][0] = MFMA16(af##S##3, bq##S##0, acc[3][0]);                             \
  acc[3][1] = MFMA16(af##S##3, bq##S##1, acc[3][1]);                             \
  acc[3][2] = MFMA16(af##S##3, bq##S##2, acc[3][2]);                             \
  acc[3][3] = MFMA16(af##S##3, bq##S##3, acc[3][3])

// Window: consume set SP, stage STG_, read set for next window RD_, wait VM_, barrier.
#define WND(SP, STG_, VM_, RD_)                                                  \
  {                                                                              \
    STG_;                                                                        \
    __builtin_amdgcn_s_setprio(1);                                               \
    MFMA16S(SP);                                                                 \
    RD_;                                                                         \
    __builtin_amdgcn_s_setprio(0);                                               \
    SGBPAT;                                                                      \
    VM_; SB; BAR; SB;                                                            \
  }

__global__ __launch_bounds__(512, 2) void gemm_qkv(const unsigned short* __restrict__ A,
                                                   const unsigned short* __restrict__ Bt,
                                                   const float* __restrict__ bias,
                                                   unsigned short* __restrict__ Qb,
                                                   unsigned short* __restrict__ Kb,
                                                   unsigned short* __restrict__ Vtb) {
  __shared__ unsigned short SH[49152];     // 96 KiB
  char* SHB = (char*)SH;
  const int tid = threadIdx.x;
  const int w = tid >> 6, lane = tid & 63, l15 = lane & 15, quad = lane >> 4;
  const int wm = w >> 2, wn = w & 3;       // 2M x 4N waves, wave tile 64x64
  // XCD-contiguous swizzle: 768 blocks, 96/XCD chunk, row-major over 12 col-tiles
  const int g = ((blockIdx.x & 7) * 96) + (blockIdx.x >> 3);
  const int bx = g % 12, by = g / 12;
  const int col0 = bx << 8, row0 = by << 7;   // BN=256, BM=128

  // ds_read swizzle: chunk ^= (row>>1)&3 within the 64B row
  const int qa = quad ^ ((l15 >> 1) & 3);
  const int abase = (wm * 64 + l15) * 64 + qa * 16;    // + i*1024 per m-frag
  const int bbase = (wn * 64 + l15) * 64 + qa * 16;    // + j*1024 per n-frag

  // staging: thread c -> LDS byte c*16 (linear); source column pre-swizzled
  const int qsw = (tid & 3) ^ ((tid >> 3) & 3);
  const unsigned short* a_src = A + (size_t)(row0 + (tid >> 2)) * 1024 + qsw * 8;
  const unsigned short* b_src = Bt + (size_t)(col0 + (tid >> 2)) * 1024 + qsw * 8;
  const int stgo = (tid & ~63) * 16;       // wave-uniform LDS byte offset

  f32x4 acc[4][4] = {};
  bf16x8 afA0, afA1, afA2, afA3, bqA0, bqA1, bqA2, bqA3;
  bf16x8 afB0, afB1, afB2, afB3, bqB0, bqB1, bqB2, bqB3;

  // prologue: batches S(0,kh0), S(0,kh1), S(1,kh0); VM3 drains the first two;
  // then read setA <- (tile0, kh0).
  STAGE3(0, 0, 0); STAGE3(0, 1, 0); STAGE3(1, 0, 1);
  VM3; SB; BAR; SB;
  RDSET(A, 0, 0);

  // J = 0..13 in pairs (buf literal): even window of J consumes setA, stages
  // S(J+1,kh1,buf (J+1)&1), reads setB <- (J,kh1,buf J&1); odd consumes setB,
  // stages S(J+2,kh0,buf J&1), reads setA <- (J+1,kh0,buf (J+1)&1).
  #pragma unroll 1
  for (int jj = 0; jj < 7; ++jj) {
    const int J0 = 2 * jj;
    WND(A, STAGE3(J0 + 1, 1, 1), VM3, RDSET(B, 0, 1))
    WND(B, STAGE3(J0 + 2, 0, 0), VM3, RDSET(A, 1, 0))
    WND(A, STAGE3(J0 + 2, 1, 0), VM3, RDSET(B, 1, 1))
    WND(B, STAGE3(J0 + 3, 0, 1), VM3, RDSET(A, 0, 0))
  }
  // J=14 (buf0): W28 stages S(15,kh1,buf1); W29 no stage, VM0 (drain last batch)
  WND(A, STAGE3(15, 1, 1), VM3, RDSET(B, 0, 1))
  WND(B, (void)0, VM0, RDSET(A, 1, 0))
  // J=15 (buf1): W30 no stage/VM; W31 MFMA only
  WND(A, (void)0, (void)0, RDSET(B, 1, 1))
  __builtin_amdgcn_s_setprio(1);
  MFMA16S(B);
  __builtin_amdgcn_s_setprio(0);
  __syncthreads();

  // ---------------- epilogue (same math/layout as verified versions; i-range 4)
  const int which = col0 >> 10;            // 0=Q, 1=K, 2=V
  const int h = ((col0 + wn * 64) >> 6) & 15;
  const int b = row0 >> 11;
  const int srow0 = (row0 & 2047) + wm * 64;
  float bv[4];
  #pragma unroll
  for (int j = 0; j < 4; ++j) {
    int nc = col0 + wn * 64 + j * 16 + l15;
    int oc = ((nc >> 6) & 15) * 192 + (nc >> 10) * 64 + (nc & 63);
    bv[j] = bias[oc];
  }
  float* Ew = (float*)SHB + w * 1072;      // per-wave 16x66 fp32 tile (aliased in SH)

  if (which < 2) {
    // ---- Q/K: [bh][s][d] row-major, 32B/thread coalesced stores
    const float sc = (which == 0) ? 0.18033688011112042f : 1.0f;  // 1/sqrt(64)*log2e
    const int lr = lane >> 2, d0 = (lane & 3) * 16;
    unsigned short* base = (which == 0 ? Qb : Kb) + ((size_t)(b * 16 + h) * 2048 + srow0) * 64;
    #pragma unroll
    for (int i = 0; i < 4; ++i) {
      #pragma unroll
      for (int j = 0; j < 4; ++j)
        #pragma unroll
        for (int r = 0; r < 4; ++r)
          Ew[(quad * 4 + r) * 66 + j * 16 + l15] = (acc[i][j][r] + bv[j]) * sc;
      float v[16];
      #pragma unroll
      for (int c = 0; c < 4; ++c)
        *(f32x4*)&v[4 * c] = *(const f32x4*)&Ew[lr * 66 + d0 + 4 * c];
      u32x4 pk0 = {pkbf(v[0], v[1]), pkbf(v[2], v[3]), pkbf(v[4], v[5]), pkbf(v[6], v[7])};
      u32x4 pk1 = {pkbf(v[8], v[9]), pkbf(v[10], v[11]), pkbf(v[12], v[13]), pkbf(v[14], v[15])};
      unsigned short* dst = base + (size_t)(i * 16 + lr) * 64 + d0;
      *(u32x4*)dst = pk0;
      *(u32x4*)(dst + 8) = pk1;
    }
  } else {
    // ---- V: transposed [bh][d][s], per-wave column reads (2-way free), 32B stores
    const int d = lane;
    unsigned short* base = Vtb + ((size_t)(b * 16 + h) * 64 + d) * 2048 + srow0;
    #pragma unroll
    for (int i = 0; i < 4; ++i) {
      #pragma unroll
      for (int j = 0; j < 4; ++j)
        #pragma unroll
        for (int r = 0; r < 4; ++r)
          Ew[(quad * 4 + r) * 66 + j * 16 + l15] = acc[i][j][r] + bv[j];
      float e[16];
      #pragma unroll
      for (int k = 0; k < 16; ++k) e[k] = Ew[k * 66 + d];
      u32x4 pk0 = {pkbf(e[0], e[1]), pkbf(e[2], e[3]), pkbf(e[4], e[5]), pkbf(e[6], e[7])};
      u32x4 pk1 = {pkbf(e[8], e[9]), pkbf(e[10], e[11]), pkbf(e[12], e[13]), pkbf(e[14], e[15])};
      unsigned short* dst = base + i * 16;
      *(u32x4*)dst = pk0;
      *(u32x4*)(dst + 8) = pk1;
    }
  }
}

// GEMM2: out = Attn @ Wo + bo (fp32 out). Attn flat [bh][s][d] == reshape quirk layout.
__global__ __launch_bounds__(256) void gemm_out(const unsigned short* __restrict__ A,
                                                const unsigned short* __restrict__ Bt,
                                                const float* __restrict__ bias,
                                                float* __restrict__ out) {
  GEMM_CORE(A, Bt)
  for (int i = 0; i < 4; ++i) {
    int grow = row0 + wm * 64 + i * 16 + quad * 4;
    for (int j = 0; j < 4; ++j) {
      int gcol = col0 + wn * 64 + j * 16 + l15;
      float bvv = bias[gcol];
      for (int r = 0; r < 4; ++r)
        out[(size_t)(grow + r) * 1024 + gcol] = acc[i][j][r] + bvv;
    }
  }
}

// ---------------------------------------------------------------- flash attention (v5)
// 512 blocks, 4 waves x 64 q-rows = 256 q/block. Per 64-key tile, K/V fragment reads
// amortize over 4 sub-tiles (2x MFMA per LDS byte vs v4). Software-pipelined staging.
// Max-free exp2 softmax (Q pre-scaled); l = per-lane VALU partials, reduced once at end.
// Diagonal zone: tile t in 0..3, wave w<t idle, w==t masks, w>t full.
__global__ __launch_bounds__(256) void attn_kernel(const unsigned short* __restrict__ Qb,
                                                   const unsigned short* __restrict__ Kb,
                                                   const unsigned short* __restrict__ Vtb,
                                                   unsigned short* __restrict__ attnout) {
  __shared__ unsigned short K0[64 * 32], K1[64 * 32];   // [k][d<32], [k][d>=32]
  __shared__ unsigned short V0[64 * 32], V1[64 * 32];   // [d][k<32], [d][k>=32]
  __shared__ unsigned short P0[4][4][512], P1[4][4][512]; // per wave/sub, swizzled
  __shared__ float Lbc[4][64];

  const int tid = threadIdx.x;
  const int w = tid >> 6, lane = tid & 63, l15 = lane & 15, quad = lane >> 4;
  // block pairing: qt such that bid and bid+256 sum to 7 (static 2-blocks/CU balance)
  const int i2 = blockIdx.x >> 6;
  const int jj = ((i2 & 1) << 1) | ((i2 >> 1) & 1);
  const int qt = (i2 & 4) ? jj : 7 - jj;
  const int bh = blockIdx.x & 63;
  const int q0w = qt * 256 + w * 64;

  const unsigned short* Qg = Qb + (size_t)bh * S_LEN * DHEAD;
  const unsigned short* Kg = Kb + (size_t)bh * S_LEN * DHEAD;
  const unsigned short* Vg = Vtb + (size_t)bh * DHEAD * S_LEN;

  // Q B-frags (n=q=l15, k=d=quad*8+j), held for whole kernel
  bf16x8 qf[4][2];
  #pragma unroll
  for (int sub = 0; sub < 4; ++sub) {
    const unsigned short* p = Qg + (size_t)(q0w + sub * 16 + l15) * DHEAD + quad * 8;
    qf[sub][0] = *(const bf16x8*)p;
    qf[sub][1] = *(const bf16x8*)(p + 32);
  }

  // staging addresses: thread -> (row = tid>>2, chunk = tid&3)
  const int srow = tid >> 2, sc8 = (tid & 3) * 8;
  const unsigned short* kgb = Kg + srow * 64 + sc8;
  const unsigned short* vgb = Vg + (size_t)srow * S_LEN + sc8;
  const int wKo = srow * 32 + sc8;

  // P swizzle (breaks b64-write conflicts; round-4 proven)
  const int psw = (l15 & 3) ^ ((l15 >> 2) & 3);
  const int pw0 = l15 * 32 + (((quad >> 1) ^ psw) << 3) + ((quad & 1) << 2);
  const int pw1 = l15 * 32 + ((((quad >> 1) + 2) ^ psw) << 3) + ((quad & 1) << 2);
  const int pro = l15 * 32 + ((quad ^ psw) << 3);
  const int kvo = l15 * 32 + quad * 8;

  f32x4 oacc[4][4] = {};
  float lacc[4] = {0.f, 0.f, 0.f, 0.f};

  const int ktdiag = 4 * qt;
  const int nkt = ktdiag + 4;

  // prologue: load tile 0
  bf16x8 kr0 = *(const bf16x8*)kgb, kr1 = *(const bf16x8*)(kgb + 32);
  bf16x8 vr0 = *(const bf16x8*)vgb, vr1 = *(const bf16x8*)(vgb + 32);

  for (int kt = 0; kt < nkt; ++kt) {
    *(bf16x8*)&K0[wKo] = kr0;  *(bf16x8*)&K1[wKo] = kr1;
    *(bf16x8*)&V0[wKo] = vr0;  *(bf16x8*)&V1[wKo] = vr1;
    __syncthreads();
    if (kt + 1 < nkt) {        // prefetch next tile while computing this one
      const unsigned short* kp = kgb + (kt + 1) * 4096;
      const unsigned short* vp = vgb + (kt + 1) * 64;
      kr0 = *(const bf16x8*)kp;  kr1 = *(const bf16x8*)(kp + 32);
      vr0 = *(const bf16x8*)vp;  vr1 = *(const bf16x8*)(vp + 32);
    }

    const int t = kt - ktdiag;              // <0: full zone, 0..3: diagonal zone
    const bool act = (t < 0) || (w >= t);

    if (act) {
      if (t < 0) {
        // ---------------- full tiles (hot path, branch-free)
        #pragma unroll
        for (int jk = 0; jk < 4; ++jk) {
          bf16x8 kf0 = *(const bf16x8*)&K0[jk * 512 + kvo];
          bf16x8 kf1 = *(const bf16x8*)&K1[jk * 512 + kvo];
          #pragma unroll
          for (int sub = 0; sub < 4; ++sub) {
            f32x4 z = {};
            z = MFMA16(kf0, qf[sub][0], z);
            z = MFMA16(kf1, qf[sub][1], z);
            float e0 = __builtin_amdgcn_exp2f(z[0]);
            float e1 = __builtin_amdgcn_exp2f(z[1]);
            float e2 = __builtin_amdgcn_exp2f(z[2]);
            float e3 = __builtin_amdgcn_exp2f(z[3]);
            lacc[sub] += (e0 + e1) + (e2 + e3);
            unsigned short* pd = (jk < 2) ? P0[w][sub] : P1[w][sub];
            *(u32x2*)&pd[(jk & 1) ? pw1 : pw0] = (u32x2){pkbf(e0, e1), pkbf(e2, e3)};
          }
        }
      } else {
        // ---------------- diagonal zone: wave w==t masks, w>t full
        const bool dg = (t == w);
        #pragma unroll
        for (int jk = 0; jk < 4; ++jk) {
          bf16x8 kf0 = *(const bf16x8*)&K0[jk * 512 + kvo];
          bf16x8 kf1 = *(const bf16x8*)&K1[jk * 512 + kvo];
          #pragma unroll
          for (int sub = 0; sub < 4; ++sub) {
            unsigned short* pd = (jk < 2) ? P0[w][sub] : P1[w][sub];
            unsigned int* dst = (unsigned int*)&pd[(jk & 1) ? pw1 : pw0];
            if (dg && jk > sub) { *(u32x2*)dst = (u32x2){0u, 0u}; continue; }
            f32x4 z = {};
            z = MFMA16(kf0, qf[sub][0], z);
            z = MFMA16(kf1, qf[sub][1], z);
            if (dg && jk == sub) {          // diagonal 16x16: mask key > query
              #pragma unroll
              for (int r = 0; r < 4; ++r)
                if (quad * 4 + r > l15) z[r] = -3e38f;
            }
            float e0 = __builtin_amdgcn_exp2f(z[0]);
            float e1 = __builtin_amdgcn_exp2f(z[1]);
            float e2 = __builtin_amdgcn_exp2f(z[2]);
            float e3 = __builtin_amdgcn_exp2f(z[3]);
            lacc[sub] += (e0 + e1) + (e2 + e3);
            *(u32x2*)dst = (u32x2){pkbf(e0, e1), pkbf(e2, e3)};
          }
        }
      }

      // ---- P A-frags, then O += P.V (V B-frags shared across all 4 subs)
      bf16x8 pf[4][2];
      #pragma unroll
      for (int sub = 0; sub < 4; ++sub) {
        pf[sub][0] = *(const bf16x8*)&P0[w][sub][pro];
        pf[sub][1] = *(const bf16x8*)&P1[w][sub][pro];
      }
      #pragma unroll
      for (int dt = 0; dt < 4; ++dt) {
        bf16x8 vb0 = *(const bf16x8*)&V0[dt * 512 + kvo];
        bf16x8 vb1 = *(const bf16x8*)&V1[dt * 512 + kvo];
        #pragma unroll
        for (int sub = 0; sub < 4; ++sub) {
          oacc[sub][dt] = MFMA16(pf[sub][0], vb0, oacc[sub][dt]);
          oacc[sub][dt] = MFMA16(pf[sub][1], vb1, oacc[sub][dt]);
        }
      }
    }
    __syncthreads();
  }

  // ---- finalize: reduce l across quads (once), broadcast via LDS, store
  #pragma unroll
  for (int sub = 0; sub < 4; ++sub) {
    float l = lacc[sub];
    l += __shfl_xor(l, 16);
    l += __shfl_xor(l, 32);
    if (quad == 0) Lbc[w][sub * 16 + l15] = l;
  }
  #pragma unroll
  for (int sub = 0; sub < 4; ++sub) {
    f32x4 l4 = *(const f32x4*)&Lbc[w][sub * 16 + quad * 4];
    int qbase = q0w + sub * 16 + quad * 4;
    unsigned short* dst = attnout + ((size_t)bh * S_LEN + qbase) * DHEAD;
    #pragma unroll
    for (int r = 0; r < 4; ++r) {
      float inv = __builtin_amdgcn_rcpf(l4[r]);
      #pragma unroll
      for (int dt = 0; dt < 4; ++dt)
        dst[(size_t)r * DHEAD + dt * 16 + l15] = f2bf(oacc[sub][dt][r] * inv);
    }
  }
}

// ---------------------------------------------------------------- launch
extern "C" void kernel_launch(void* const* d_in, const int* in_sizes, int n_in,
                              void* d_out, int out_size, void* d_ws, size_t ws_size,
                              hipStream_t stream) {
  const float* x    = (const float*)d_in[0];
  // d_in[1] = mask: deterministic tril, causality applied analytically
  const float* Wqkv = (const float*)d_in[2];
  const float* bqkv = (const float*)d_in[3];
  const float* Wo   = (const float*)d_in[4];
  const float* bo   = (const float*)d_in[5];
  float* out = (float*)d_out;

  char* ws = (char*)d_ws;
  unsigned short* Xbf   = (unsigned short*)(ws);                 // 16 MB
  unsigned short* WqkvT = (unsigned short*)(ws + 16777216);      // 6 MB (permuted)
  unsigned short* WoT   = (unsigned short*)(ws + 23068672);      // 2 MB
  unsigned short* Qb    = (unsigned short*)(ws + 25165824);      // 16.78 MB
  unsigned short* Kb    = (unsigned short*)(ws + 41943040);      // 16.78 MB
  unsigned short* Vtb   = (unsigned short*)(ws + 58720256);      // 16.78 MB  [bh][d][s]
  unsigned short* Attn  = (unsigned short*)(ws + 75497472);      // 16.78 MB

  cast_bf16<<<8192, 256, 0, stream>>>(x, Xbf, MROWS * 1024);
  transpose_cast_qkv<<<dim3(96, 32), dim3(32, 8), 0, stream>>>(Wqkv, WqkvT);
  transpose_cast<<<dim3(32, 32), dim3(32, 8), 0, stream>>>(Wo, WoT, 1024, 1024);
  gemm_qkv<<<768, 512, 0, stream>>>(Xbf, WqkvT, bqkv, Qb, Kb, Vtb);
  attn_kernel<<<512, 256, 0, stream>>>(Qb, Kb, Vtb, Attn);
  gemm_out<<<dim3(8, 64), 256, 0, stream>>>(Attn, WoT, bo, out);
}

// Round 4
// 269.778 us; speedup vs baseline: 1.0202x; 1.0202x over previous
//
#include <hip/hip_runtime.h>

// ---------------------------------------------------------------- types
typedef __attribute__((ext_vector_type(8))) short bf16x8;   // 8 bf16 (4 VGPR)
typedef __attribute__((ext_vector_type(4))) float f32x4;
typedef __attribute__((ext_vector_type(2))) unsigned int u32x2;
typedef __attribute__((ext_vector_type(4))) unsigned int u32x4;

#define MFMA16(a, b, c) __builtin_amdgcn_mfma_f32_16x16x32_bf16((a), (b), (c), 0, 0, 0)

// B=4, S=2048, E=1024, H=16, D=64
#define S_LEN 2048
#define NHEAD 16
#define DHEAD 64
#define BH    64            // B*H
#define MROWS 8192          // B*S

__device__ __forceinline__ unsigned short f2bf(float f) {
  unsigned int u = __builtin_bit_cast(unsigned int, f);
  u += 0x7FFFu + ((u >> 16) & 1u);          // round-to-nearest-even
  return (unsigned short)(u >> 16);
}

__device__ __forceinline__ void gl_lds16(const void* g, void* l) {
  __builtin_amdgcn_global_load_lds(
      (const __attribute__((address_space(1))) void*)g,
      (__attribute__((address_space(3))) void*)l, 16, 0, 0);
}

// pack two fp32 -> (bf16(hi)<<16)|bf16(lo), round-half-up via add+perm
__device__ __forceinline__ unsigned int pkbf(float lo, float hi) {
  unsigned int ulo = __builtin_bit_cast(unsigned int, lo) + 0x8000u;
  unsigned int uhi = __builtin_bit_cast(unsigned int, hi) + 0x8000u;
  return __builtin_amdgcn_perm(uhi, ulo, 0x07060302u);
}

// ---------------------------------------------------------------- cast fp32 -> bf16
__global__ __launch_bounds__(256) void cast_bf16(const float* __restrict__ src,
                                                 unsigned short* __restrict__ dst, int n) {
  int i = (blockIdx.x * 256 + threadIdx.x) * 4;
  if (i + 3 < n) {
    f32x4 v = *(const f32x4*)(src + i);
    unsigned long long pk =
        (unsigned long long)f2bf(v[0]) |
        ((unsigned long long)f2bf(v[1]) << 16) |
        ((unsigned long long)f2bf(v[2]) << 32) |
        ((unsigned long long)f2bf(v[3]) << 48);
    *(unsigned long long*)(dst + i) = pk;
  }
}

// ---------------------------------------------------------------- transpose + cast (plain, for Wo)
__global__ __launch_bounds__(256) void transpose_cast(const float* __restrict__ src,
                                                      unsigned short* __restrict__ dst,
                                                      int R, int C) {
  __shared__ float tile[32][33];
  int c0 = blockIdx.x * 32, r0 = blockIdx.y * 32;
  int tx = threadIdx.x, ty = threadIdx.y;   // block (32,8)
  for (int i = 0; i < 32; i += 8)
    tile[ty + i][tx] = src[(size_t)(r0 + ty + i) * C + c0 + tx];
  __syncthreads();
  for (int i = 0; i < 32; i += 8)
    dst[(size_t)(c0 + ty + i) * R + r0 + tx] = f2bf(tile[tx][ty + i]);
}

// ---------------------------------------------------------------- transpose + cast + col-permute for Wqkv
// src [1024 k][3072 oc], oc = h*192 + which*64 + d  ->  dst[nc][1024], nc = which*1024 + h*64 + d
__global__ __launch_bounds__(256) void transpose_cast_qkv(const float* __restrict__ src,
                                                          unsigned short* __restrict__ dst) {
  __shared__ float tile[32][33];
  int c0 = blockIdx.x * 32, r0 = blockIdx.y * 32;
  int tx = threadIdx.x, ty = threadIdx.y;   // block (32,8)
  for (int i = 0; i < 32; i += 8)
    tile[ty + i][tx] = src[(size_t)(r0 + ty + i) * 3072 + c0 + tx];
  __syncthreads();
  for (int i = 0; i < 32; i += 8) {
    int oc = c0 + ty + i;
    int h = oc / 192, rr = oc % 192;
    int nc = ((rr >> 6) << 10) + (h << 6) + (rr & 63);
    dst[(size_t)nc * 1024 + r0 + tx] = f2bf(tile[tx][ty + i]);
  }
}

// ---------------------------------------------------------------- GEMM core (m97 structure, kept for gemm_out)
#define GEMM_CORE(A_, Bt_)                                                              \
  __shared__ unsigned short As[128 * 32];                                               \
  __shared__ unsigned short Bs[128 * 32];                                               \
  const int tid = threadIdx.x;                                                          \
  const int w = tid >> 6, lane = tid & 63, l15 = lane & 15, quad = lane >> 4;           \
  const int wm = w >> 1, wn = w & 1;                                                    \
  const int col0 = blockIdx.x * 128, row0 = blockIdx.y * 128;                           \
  f32x4 acc[4][4] = {};                                                                 \
  for (int kt = 0; kt < 32; ++kt) {                                                     \
    const int k0 = kt * 32;                                                             \
    for (int p = 0; p < 2; ++p) {                                                       \
      int c = p * 256 + tid;                                                            \
      int m = c >> 2, k8 = (c & 3) * 8;                                                 \
      void* ldsA = (char*)As + (size_t)(p * 256 + (tid & 192)) * 16;                    \
      void* ldsB = (char*)Bs + (size_t)(p * 256 + (tid & 192)) * 16;                    \
      gl_lds16(A_ + (size_t)(row0 + m) * 1024 + k0 + k8, ldsA);                         \
      gl_lds16(Bt_ + (size_t)(col0 + m) * 1024 + k0 + k8, ldsB);                        \
    }                                                                                   \
    __syncthreads();                                                                    \
    bf16x8 af[4], bfr[4];                                                               \
    for (int i = 0; i < 4; ++i)                                                         \
      af[i] = *(const bf16x8*)&As[(wm * 64 + i * 16 + l15) * 32 + quad * 8];            \
    for (int j = 0; j < 4; ++j)                                                         \
      bfr[j] = *(const bf16x8*)&Bs[(wn * 64 + j * 16 + l15) * 32 + quad * 8];           \
    for (int i = 0; i < 4; ++i)                                                         \
      for (int j = 0; j < 4; ++j)                                                       \
        acc[i][j] = MFMA16(af[i], bfr[j], acc[i][j]);                                   \
    __syncthreads();                                                                    \
  }

// ================================================================ gemm_qkv
// Faithful m201 port: 256x256 tile, BK=64, 8 waves (2M x 4N), wave tile 128x64,
// acc[8][4], LDS 128KB = 2buf x {A-h0,A-h1,B-h0,B-h1} (16KB halves, 128 rows x 128B).
// Phase p of K-tile T: (mh,kh) in order (0,0),(0,1),(1,0),(1,1):
//   { ds_read 4 A-frags (+4 B-frags on kh-change, held in regs across mh);
//     stage one half-tile; BAR; lgkmcnt(0); setprio1; 16 MFMA; setprio0; BAR }
// Stagger (WAR/RAW audited): A(T+1) halves at (T,p0/p1) -> other buf (its A last
// read (T-1,p3)); B(T+2) halves at (T,p2/p3) -> current buf (B last LDS read is p1).
// One vmcnt(4) per K-tile at p3 (leaves exactly the 2 in-flight B stages; min
// issue->wait slack 2 phases ~1650cy > HBM latency). Chunk-XOR swizzle c^=(row&7)
// on 128B rows -> 2-way-free b128 frag reads; staging source pre-swizzled, LDS linear.

#define VM4 asm volatile("s_waitcnt vmcnt(4)" ::: "memory")
#define VM0 asm volatile("s_waitcnt vmcnt(0)" ::: "memory")
#define LGKM0 asm volatile("s_waitcnt lgkmcnt(0)" ::: "memory")
#define BAR __builtin_amdgcn_s_barrier()
#define SB  __builtin_amdgcn_sched_barrier(0)

// LDS map (bytes, buf stride 65536): A-h @ h*16384; B-h @ 32768 + h*16384.
// half-tile = 128 rows x 64 k = 16KB; thread t -> bytes t*16 (+8192 for rows 64-127).
#define STAGE_AH(T, H)                                                           \
  do {                                                                           \
    char* lb_ = SHB + (((T) & 1) * 65536 + (H) * 16384) + stgo;                  \
    const unsigned short* gs_ = a_src + (size_t)(H) * 131072 + (T) * 64;         \
    gl_lds16(gs_, lb_);                                                          \
    gl_lds16(gs_ + 65536, lb_ + 8192);                                           \
  } while (0)
#define STAGE_BH(T, H)                                                           \
  do {                                                                           \
    char* lb_ = SHB + (((T) & 1) * 65536 + 32768 + (H) * 16384) + stgo;          \
    const unsigned short* gs_ = b_src + (size_t)(H) * 131072 + (T) * 64;         \
    gl_lds16(gs_, lb_);                                                          \
    gl_lds16(gs_ + 65536, lb_ + 8192);                                           \
  } while (0)

#define RD_A4(BUF, MH, KH)                                                       \
  do {                                                                           \
    const char* p_ = SHB + (BUF) * 65536 + awave + (MH) * 8192 + (ck ^ ((KH) * 64)); \
    af0 = *(const bf16x8*)(p_);                                                  \
    af1 = *(const bf16x8*)(p_ + 2048);                                           \
    af2 = *(const bf16x8*)(p_ + 4096);                                           \
    af3 = *(const bf16x8*)(p_ + 6144);                                           \
  } while (0)
#define RD_B4(BUF, S, KH)                                                        \
  do {                                                                           \
    const char* p_ = SHB + (BUF) * 65536 + bwave + (ck ^ ((KH) * 64));           \
    bq##S##0 = *(const bf16x8*)(p_);                                             \
    bq##S##1 = *(const bf16x8*)(p_ + 2048);                                      \
    bq##S##2 = *(const bf16x8*)(p_ + 4096);                                      \
    bq##S##3 = *(const bf16x8*)(p_ + 6144);                                      \
  } while (0)

#define MF16(MH, S)                                                              \
  __builtin_amdgcn_s_setprio(1);                                                 \
  acc[(MH)*4+0][0] = MFMA16(af0, bq##S##0, acc[(MH)*4+0][0]);                    \
  acc[(MH)*4+0][1] = MFMA16(af0, bq##S##1, acc[(MH)*4+0][1]);                    \
  acc[(MH)*4+0][2] = MFMA16(af0, bq##S##2, acc[(MH)*4+0][2]);                    \
  acc[(MH)*4+0][3] = MFMA16(af0, bq##S##3, acc[(MH)*4+0][3]);                    \
  acc[(MH)*4+1][0] = MFMA16(af1, bq##S##0, acc[(MH)*4+1][0]);                    \
  acc[(MH)*4+1][1] = MFMA16(af1, bq##S##1, acc[(MH)*4+1][1]);                    \
  acc[(MH)*4+1][2] = MFMA16(af1, bq##S##2, acc[(MH)*4+1][2]);                    \
  acc[(MH)*4+1][3] = MFMA16(af1, bq##S##3, acc[(MH)*4+1][3]);                    \
  acc[(MH)*4+2][0] = MFMA16(af2, bq##S##0, acc[(MH)*4+2][0]);                    \
  acc[(MH)*4+2][1] = MFMA16(af2, bq##S##1, acc[(MH)*4+2][1]);                    \
  acc[(MH)*4+2][2] = MFMA16(af2, bq##S##2, acc[(MH)*4+2][2]);                    \
  acc[(MH)*4+2][3] = MFMA16(af2, bq##S##3, acc[(MH)*4+2][3]);                    \
  acc[(MH)*4+3][0] = MFMA16(af3, bq##S##0, acc[(MH)*4+3][0]);                    \
  acc[(MH)*4+3][1] = MFMA16(af3, bq##S##1, acc[(MH)*4+3][1]);                    \
  acc[(MH)*4+3][2] = MFMA16(af3, bq##S##2, acc[(MH)*4+3][2]);                    \
  acc[(MH)*4+3][3] = MFMA16(af3, bq##S##3, acc[(MH)*4+3][3]);                    \
  __builtin_amdgcn_s_setprio(0)

// One K-tile = 4 two-barrier phases (m201 template).
#define KTILE4(BUF, T, GA, GB, WAIT_)                                            \
  { /* p0: (mh0,k0) */                                                           \
    RD_A4(BUF, 0, 0);                                                            \
    RD_B4(BUF, A, 0);                                                            \
    if (GA) STAGE_AH((T) + 1, 0);                                                \
    SB; BAR;                                                                     \
    LGKM0; SB;                                                                   \
    MF16(0, A);                                                                  \
    SB; BAR;                                                                     \
  }                                                                              \
  { /* p1: (mh0,k1) */                                                           \
    RD_A4(BUF, 0, 1);                                                            \
    RD_B4(BUF, B, 1);                                                            \
    if (GA) STAGE_AH((T) + 1, 1);                                                \
    SB; BAR;                                                                     \
    LGKM0; SB;                                                                   \
    MF16(0, B);                                                                  \
    SB; BAR;                                                                     \
  }                                                                              \
  { /* p2: (mh1,k0) */                                                           \
    RD_A4(BUF, 1, 0);                                                            \
    if (GB) STAGE_BH((T) + 2, 0);                                                \
    SB; BAR;                                                                     \
    LGKM0; SB;                                                                   \
    MF16(1, A);                                                                  \
    SB; BAR;                                                                     \
  }                                                                              \
  { /* p3: (mh1,k1) */                                                           \
    RD_A4(BUF, 1, 1);                                                            \
    if (GB) STAGE_BH((T) + 2, 1);                                                \
    SB; BAR;                                                                     \
    LGKM0; SB;                                                                   \
    MF16(1, B);                                                                  \
    WAIT_;                                                                       \
    SB; BAR;                                                                     \
  }

__global__ __launch_bounds__(512, 2) void gemm_qkv(const unsigned short* __restrict__ A,
                                                   const unsigned short* __restrict__ Bt,
                                                   const float* __restrict__ bias,
                                                   unsigned short* __restrict__ Qb,
                                                   unsigned short* __restrict__ Kb,
                                                   unsigned short* __restrict__ Vtb) {
  __shared__ unsigned short SH[65536];     // 128 KiB
  char* SHB = (char*)SH;
  const int tid = threadIdx.x;
  const int w = tid >> 6, lane = tid & 63, l15 = lane & 15, quad = lane >> 4;
  const int wm = w >> 2, wn = w & 3;       // 2M x 4N waves, wave tile 128x64
  // XCD-contiguous swizzle: 384 blocks, 48/XCD chunk, row-major over 12 col-tiles
  const int g = ((blockIdx.x & 7) * 48) + (blockIdx.x >> 3);
  const int bx = g % 12, by = g / 12;
  const int col0 = bx << 8, row0 = by << 8;

  // frag-read addressing: row*128B + swizzled chunk ((kh*4+quad)^(l15&7))*16
  const int ck = (quad ^ (l15 & 7)) << 4;                 // kh=1: ^64
  const int awave = wm * 16384 + l15 * 128;               // + mh*8192 + i*2048
  const int bwave = 32768 + (wn >> 1) * 16384 + (wn & 1) * 8192 + l15 * 128;  // + j*2048

  // staging: thread t -> LDS byte t*16 (linear); row = t>>3, source chunk pre-swizzled
  const int stgc = (tid & 7) ^ ((tid >> 3) & 7);
  const unsigned short* a_src = A + (size_t)(row0 + (tid >> 3)) * 1024 + stgc * 8;
  const unsigned short* b_src = Bt + (size_t)(col0 + (tid >> 3)) * 1024 + stgc * 8;
  const int stgo = (tid & ~63) * 16;       // wave-uniform LDS byte offset

  f32x4 acc[8][4] = {};
  bf16x8 af0, af1, af2, af3;
  bf16x8 bqA0, bqA1, bqA2, bqA3, bqB0, bqB1, bqB2, bqB3;

  // prologue: T0 all 4 halves + T1's B halves (T1's A comes from loop at (0,p0/p1));
  // vmcnt(4) = T0's 8 loads landed, T1-B's 4 in flight.
  STAGE_AH(0, 0); STAGE_AH(0, 1); STAGE_BH(0, 0); STAGE_BH(0, 1);
  STAGE_BH(1, 0); STAGE_BH(1, 1);
  VM4; SB; BAR; SB;

  #pragma unroll 1
  for (int jj = 0; jj < 7; ++jj) {
    const int T0 = 2 * jj;
    KTILE4(0, T0,     1, 1, VM4)
    KTILE4(1, T0 + 1, 1, 1, VM4)
  }
  // T=14: stage A(15) only; drain all at p3. T=15: no stages/waits.
  KTILE4(0, 14, 1, 0, VM0)
  KTILE4(1, 15, 0, 0, (void)0)
  __syncthreads();

  // ---------------- epilogue (same math/layout as verified 256^2 version)
  const int which = col0 >> 10;            // 0=Q, 1=K, 2=V
  const int h = ((col0 + wn * 64) >> 6) & 15;
  const int b = row0 >> 11;
  const int srow0 = (row0 & 2047) + wm * 128;
  float bv[4];
  #pragma unroll
  for (int j = 0; j < 4; ++j) {
    int nc = col0 + wn * 64 + j * 16 + l15;
    int oc = ((nc >> 6) & 15) * 192 + (nc >> 10) * 64 + (nc & 63);
    bv[j] = bias[oc];
  }
  float* Ew = (float*)SHB + w * 1072;      // per-wave 16x66 fp32 tile (aliased in SH)

  if (which < 2) {
    // ---- Q/K: [bh][s][d] row-major, 32B/thread coalesced stores
    const float sc = (which == 0) ? 0.18033688011112042f : 1.0f;  // 1/sqrt(64)*log2e
    const int lr = lane >> 2, d0 = (lane & 3) * 16;
    unsigned short* base = (which == 0 ? Qb : Kb) + ((size_t)(b * 16 + h) * 2048 + srow0) * 64;
    #pragma unroll
    for (int i = 0; i < 8; ++i) {
      #pragma unroll
      for (int j = 0; j < 4; ++j)
        #pragma unroll
        for (int r = 0; r < 4; ++r)
          Ew[(quad * 4 + r) * 66 + j * 16 + l15] = (acc[i][j][r] + bv[j]) * sc;
      float v[16];
      #pragma unroll
      for (int c = 0; c < 4; ++c)
        *(f32x4*)&v[4 * c] = *(const f32x4*)&Ew[lr * 66 + d0 + 4 * c];
      u32x4 pk0 = {pkbf(v[0], v[1]), pkbf(v[2], v[3]), pkbf(v[4], v[5]), pkbf(v[6], v[7])};
      u32x4 pk1 = {pkbf(v[8], v[9]), pkbf(v[10], v[11]), pkbf(v[12], v[13]), pkbf(v[14], v[15])};
      unsigned short* dst = base + (size_t)(i * 16 + lr) * 64 + d0;
      *(u32x4*)dst = pk0;
      *(u32x4*)(dst + 8) = pk1;
    }
  } else {
    // ---- V: transposed [bh][d][s], per-wave column reads (2-way free), 32B stores
    const int d = lane;
    unsigned short* base = Vtb + ((size_t)(b * 16 + h) * 64 + d) * 2048 + srow0;
    #pragma unroll
    for (int i = 0; i < 8; ++i) {
      #pragma unroll
      for (int j = 0; j < 4; ++j)
        #pragma unroll
        for (int r = 0; r < 4; ++r)
          Ew[(quad * 4 + r) * 66 + j * 16 + l15] = acc[i][j][r] + bv[j];
      float e[16];
      #pragma unroll
      for (int k = 0; k < 16; ++k) e[k] = Ew[k * 66 + d];
      u32x4 pk0 = {pkbf(e[0], e[1]), pkbf(e[2], e[3]), pkbf(e[4], e[5]), pkbf(e[6], e[7])};
      u32x4 pk1 = {pkbf(e[8], e[9]), pkbf(e[10], e[11]), pkbf(e[12], e[13]), pkbf(e[14], e[15])};
      unsigned short* dst = base + i * 16;
      *(u32x4*)dst = pk0;
      *(u32x4*)(dst + 8) = pk1;
    }
  }
}

// GEMM2: out = Attn @ Wo + bo (fp32 out). Attn flat [bh][s][d] == reshape quirk layout.
__global__ __launch_bounds__(256) void gemm_out(const unsigned short* __restrict__ A,
                                                const unsigned short* __restrict__ Bt,
                                                const float* __restrict__ bias,
                                                float* __restrict__ out) {
  GEMM_CORE(A, Bt)
  for (int i = 0; i < 4; ++i) {
    int grow = row0 + wm * 64 + i * 16 + quad * 4;
    for (int j = 0; j < 4; ++j) {
      int gcol = col0 + wn * 64 + j * 16 + l15;
      float bvv = bias[gcol];
      for (int r = 0; r < 4; ++r)
        out[(size_t)(grow + r) * 1024 + gcol] = acc[i][j][r] + bvv;
    }
  }
}

// ---------------------------------------------------------------- flash attention (v5)
// 512 blocks, 4 waves x 64 q-rows = 256 q/block. Per 64-key tile, K/V fragment reads
// amortize over 4 sub-tiles (2x MFMA per LDS byte vs v4). Software-pipelined staging.
// Max-free exp2 softmax (Q pre-scaled); l = per-lane VALU partials, reduced once at end.
// Diagonal zone: tile t in 0..3, wave w<t idle, w==t masks, w>t full.
__global__ __launch_bounds__(256) void attn_kernel(const unsigned short* __restrict__ Qb,
                                                   const unsigned short* __restrict__ Kb,
                                                   const unsigned short* __restrict__ Vtb,
                                                   unsigned short* __restrict__ attnout) {
  __shared__ unsigned short K0[64 * 32], K1[64 * 32];   // [k][d<32], [k][d>=32]
  __shared__ unsigned short V0[64 * 32], V1[64 * 32];   // [d][k<32], [d][k>=32]
  __shared__ unsigned short P0[4][4][512], P1[4][4][512]; // per wave/sub, swizzled
  __shared__ float Lbc[4][64];

  const int tid = threadIdx.x;
  const int w = tid >> 6, lane = tid & 63, l15 = lane & 15, quad = lane >> 4;
  // block pairing: qt such that bid and bid+256 sum to 7 (static 2-blocks/CU balance)
  const int i2 = blockIdx.x >> 6;
  const int jj = ((i2 & 1) << 1) | ((i2 >> 1) & 1);
  const int qt = (i2 & 4) ? jj : 7 - jj;
  const int bh = blockIdx.x & 63;
  const int q0w = qt * 256 + w * 64;

  const unsigned short* Qg = Qb + (size_t)bh * S_LEN * DHEAD;
  const unsigned short* Kg = Kb + (size_t)bh * S_LEN * DHEAD;
  const unsigned short* Vg = Vtb + (size_t)bh * DHEAD * S_LEN;

  // Q B-frags (n=q=l15, k=d=quad*8+j), held for whole kernel
  bf16x8 qf[4][2];
  #pragma unroll
  for (int sub = 0; sub < 4; ++sub) {
    const unsigned short* p = Qg + (size_t)(q0w + sub * 16 + l15) * DHEAD + quad * 8;
    qf[sub][0] = *(const bf16x8*)p;
    qf[sub][1] = *(const bf16x8*)(p + 32);
  }

  // staging addresses: thread -> (row = tid>>2, chunk = tid&3)
  const int srow = tid >> 2, sc8 = (tid & 3) * 8;
  const unsigned short* kgb = Kg + srow * 64 + sc8;
  const unsigned short* vgb = Vg + (size_t)srow * S_LEN + sc8;
  const int wKo = srow * 32 + sc8;

  // P swizzle (breaks b64-write conflicts; round-4 proven)
  const int psw = (l15 & 3) ^ ((l15 >> 2) & 3);
  const int pw0 = l15 * 32 + (((quad >> 1) ^ psw) << 3) + ((quad & 1) << 2);
  const int pw1 = l15 * 32 + ((((quad >> 1) + 2) ^ psw) << 3) + ((quad & 1) << 2);
  const int pro = l15 * 32 + ((quad ^ psw) << 3);
  const int kvo = l15 * 32 + quad * 8;

  f32x4 oacc[4][4] = {};
  float lacc[4] = {0.f, 0.f, 0.f, 0.f};

  const int ktdiag = 4 * qt;
  const int nkt = ktdiag + 4;

  // prologue: load tile 0
  bf16x8 kr0 = *(const bf16x8*)kgb, kr1 = *(const bf16x8*)(kgb + 32);
  bf16x8 vr0 = *(const bf16x8*)vgb, vr1 = *(const bf16x8*)(vgb + 32);

  for (int kt = 0; kt < nkt; ++kt) {
    *(bf16x8*)&K0[wKo] = kr0;  *(bf16x8*)&K1[wKo] = kr1;
    *(bf16x8*)&V0[wKo] = vr0;  *(bf16x8*)&V1[wKo] = vr1;
    __syncthreads();
    if (kt + 1 < nkt) {        // prefetch next tile while computing this one
      const unsigned short* kp = kgb + (kt + 1) * 4096;
      const unsigned short* vp = vgb + (kt + 1) * 64;
      kr0 = *(const bf16x8*)kp;  kr1 = *(const bf16x8*)(kp + 32);
      vr0 = *(const bf16x8*)vp;  vr1 = *(const bf16x8*)(vp + 32);
    }

    const int t = kt - ktdiag;              // <0: full zone, 0..3: diagonal zone
    const bool act = (t < 0) || (w >= t);

    if (act) {
      if (t < 0) {
        // ---------------- full tiles (hot path, branch-free)
        #pragma unroll
        for (int jk = 0; jk < 4; ++jk) {
          bf16x8 kf0 = *(const bf16x8*)&K0[jk * 512 + kvo];
          bf16x8 kf1 = *(const bf16x8*)&K1[jk * 512 + kvo];
          #pragma unroll
          for (int sub = 0; sub < 4; ++sub) {
            f32x4 z = {};
            z = MFMA16(kf0, qf[sub][0], z);
            z = MFMA16(kf1, qf[sub][1], z);
            float e0 = __builtin_amdgcn_exp2f(z[0]);
            float e1 = __builtin_amdgcn_exp2f(z[1]);
            float e2 = __builtin_amdgcn_exp2f(z[2]);
            float e3 = __builtin_amdgcn_exp2f(z[3]);
            lacc[sub] += (e0 + e1) + (e2 + e3);
            unsigned short* pd = (jk < 2) ? P0[w][sub] : P1[w][sub];
            *(u32x2*)&pd[(jk & 1) ? pw1 : pw0] = (u32x2){pkbf(e0, e1), pkbf(e2, e3)};
          }
        }
      } else {
        // ---------------- diagonal zone: wave w==t masks, w>t full
        const bool dg = (t == w);
        #pragma unroll
        for (int jk = 0; jk < 4; ++jk) {
          bf16x8 kf0 = *(const bf16x8*)&K0[jk * 512 + kvo];
          bf16x8 kf1 = *(const bf16x8*)&K1[jk * 512 + kvo];
          #pragma unroll
          for (int sub = 0; sub < 4; ++sub) {
            unsigned short* pd = (jk < 2) ? P0[w][sub] : P1[w][sub];
            unsigned int* dst = (unsigned int*)&pd[(jk & 1) ? pw1 : pw0];
            if (dg && jk > sub) { *(u32x2*)dst = (u32x2){0u, 0u}; continue; }
            f32x4 z = {};
            z = MFMA16(kf0, qf[sub][0], z);
            z = MFMA16(kf1, qf[sub][1], z);
            if (dg && jk == sub) {          // diagonal 16x16: mask key > query
              #pragma unroll
              for (int r = 0; r < 4; ++r)
                if (quad * 4 + r > l15) z[r] = -3e38f;
            }
            float e0 = __builtin_amdgcn_exp2f(z[0]);
            float e1 = __builtin_amdgcn_exp2f(z[1]);
            float e2 = __builtin_amdgcn_exp2f(z[2]);
            float e3 = __builtin_amdgcn_exp2f(z[3]);
            lacc[sub] += (e0 + e1) + (e2 + e3);
            *(u32x2*)dst = (u32x2){pkbf(e0, e1), pkbf(e2, e3)};
          }
        }
      }

      // ---- P A-frags, then O += P.V (V B-frags shared across all 4 subs)
      bf16x8 pf[4][2];
      #pragma unroll
      for (int sub = 0; sub < 4; ++sub) {
        pf[sub][0] = *(const bf16x8*)&P0[w][sub][pro];
        pf[sub][1] = *(const bf16x8*)&P1[w][sub][pro];
      }
      #pragma unroll
      for (int dt = 0; dt < 4; ++dt) {
        bf16x8 vb0 = *(const bf16x8*)&V0[dt * 512 + kvo];
        bf16x8 vb1 = *(const bf16x8*)&V1[dt * 512 + kvo];
        #pragma unroll
        for (int sub = 0; sub < 4; ++sub) {
          oacc[sub][dt] = MFMA16(pf[sub][0], vb0, oacc[sub][dt]);
          oacc[sub][dt] = MFMA16(pf[sub][1], vb1, oacc[sub][dt]);
        }
      }
    }
    __syncthreads();
  }

  // ---- finalize: reduce l across quads (once), broadcast via LDS, store
  #pragma unroll
  for (int sub = 0; sub < 4; ++sub) {
    float l = lacc[sub];
    l += __shfl_xor(l, 16);
    l += __shfl_xor(l, 32);
    if (quad == 0) Lbc[w][sub * 16 + l15] = l;
  }
  #pragma unroll
  for (int sub = 0; sub < 4; ++sub) {
    f32x4 l4 = *(const f32x4*)&Lbc[w][sub * 16 + quad * 4];
    int qbase = q0w + sub * 16 + quad * 4;
    unsigned short* dst = attnout + ((size_t)bh * S_LEN + qbase) * DHEAD;
    #pragma unroll
    for (int r = 0; r < 4; ++r) {
      float inv = __builtin_amdgcn_rcpf(l4[r]);
      #pragma unroll
      for (int dt = 0; dt < 4; ++dt)
        dst[(size_t)r * DHEAD + dt * 16 + l15] = f2bf(oacc[sub][dt][r] * inv);
    }
  }
}

// ---------------------------------------------------------------- launch
extern "C" void kernel_launch(void* const* d_in, const int* in_sizes, int n_in,
                              void* d_out, int out_size, void* d_ws, size_t ws_size,
                              hipStream_t stream) {
  const float* x    = (const float*)d_in[0];
  // d_in[1] = mask: deterministic tril, causality applied analytically
  const float* Wqkv = (const float*)d_in[2];
  const float* bqkv = (const float*)d_in[3];
  const float* Wo   = (const float*)d_in[4];
  const float* bo   = (const float*)d_in[5];
  float* out = (float*)d_out;

  char* ws = (char*)d_ws;
  unsigned short* Xbf   = (unsigned short*)(ws);                 // 16 MB
  unsigned short* WqkvT = (unsigned short*)(ws + 16777216);      // 6 MB (permuted)
  unsigned short* WoT   = (unsigned short*)(ws + 23068672);      // 2 MB
  unsigned short* Qb    = (unsigned short*)(ws + 25165824);      // 16.78 MB
  unsigned short* Kb    = (unsigned short*)(ws + 41943040);      // 16.78 MB
  unsigned short* Vtb   = (unsigned short*)(ws + 58720256);      // 16.78 MB  [bh][d][s]
  unsigned short* Attn  = (unsigned short*)(ws + 75497472);      // 16.78 MB

  cast_bf16<<<8192, 256, 0, stream>>>(x, Xbf, MROWS * 1024);
  transpose_cast_qkv<<<dim3(96, 32), dim3(32, 8), 0, stream>>>(Wqkv, WqkvT);
  transpose_cast<<<dim3(32, 32), dim3(32, 8), 0, stream>>>(Wo, WoT, 1024, 1024);
  gemm_qkv<<<384, 512, 0, stream>>>(Xbf, WqkvT, bqkv, Qb, Kb, Vtb);
  attn_kernel<<<512, 256, 0, stream>>>(Qb, Kb, Vtb, Attn);
  gemm_out<<<dim3(8, 64), 256, 0, stream>>>(Attn, WoT, bo, out);
}